// Round 5
// baseline (2718.694 us; speedup 1.0000x reference)
//
#include <hip/hip_runtime.h>
#include <stdint.h>

#define NNODES 20000
#define NEDGES 160000
#define NPAD   20096   // 157 * 128

typedef float f32x4 __attribute__((ext_vector_type(4)));
typedef short s16x8 __attribute__((ext_vector_type(8)));

__device__ __forceinline__ float b2f(unsigned short b) {
    unsigned int u = ((unsigned int)b) << 16;
    return __builtin_bit_cast(float, u);
}
__device__ __forceinline__ unsigned short f2b(float f) {
    unsigned int u = __builtin_bit_cast(unsigned int, f);
    unsigned int r = (u + 0x7FFFu + ((u >> 16) & 1u)) >> 16;
    return (unsigned short)r;
}
__device__ __forceinline__ float sigm(float x) {
    return 1.0f / (1.0f + __expf(-x));
}
__device__ __forceinline__ float softp(float x) {
    return fmaxf(x, 0.f) + __logf(1.f + __expf(-fabsf(x)));
}

// ---- GEMM: C[M,N] = A[M,K](bf16) @ BT[N,K]^T(bf16); C fp32 or bf16 ----
// M%128==0, N%128==0, K%32==0. 256 threads, 128x128 tile, 4 waves (2x2 of 64x64)
__global__ __launch_bounds__(256) void gemm_bt_kernel(
    const unsigned short* __restrict__ A,
    const unsigned short* __restrict__ BT,
    float* __restrict__ Cf,
    unsigned short* __restrict__ Cb,   // if non-null, write bf16 here instead
    int M, int N, int K)
{
    __shared__ unsigned short As[128 * 32];
    __shared__ unsigned short Bs[128 * 32];
    const int tid  = threadIdx.x;
    const int wid  = tid >> 6;
    const int lane = tid & 63;
    const int bm = blockIdx.x * 128;
    const int bn = blockIdx.y * 128;
    const int wm = (wid & 1) * 64;
    const int wn = (wid >> 1) * 64;

    f32x4 acc[4][4];
#pragma unroll
    for (int i = 0; i < 4; i++)
#pragma unroll
        for (int j = 0; j < 4; j++) acc[i][j] = {0.f, 0.f, 0.f, 0.f};

    for (int k0 = 0; k0 < K; k0 += 32) {
#pragma unroll
        for (int r = 0; r < 2; r++) {
            int flat = r * 256 + tid;          // 0..511
            int row  = flat >> 2;              // tile row
            int part = flat & 3;               // 8-elem chunk within 32-wide row
            const unsigned short* ga = A  + (size_t)(bm + row) * K + k0 + part * 8;
            const unsigned short* gb = BT + (size_t)(bn + row) * K + k0 + part * 8;
            __builtin_amdgcn_global_load_lds(
                (const __attribute__((address_space(1))) unsigned int*)ga,
                (__attribute__((address_space(3))) unsigned int*)&As[flat * 8], 16, 0, 0);
            __builtin_amdgcn_global_load_lds(
                (const __attribute__((address_space(1))) unsigned int*)gb,
                (__attribute__((address_space(3))) unsigned int*)&Bs[flat * 8], 16, 0, 0);
        }
        __syncthreads();

        const int kq = (lane >> 4) * 8;
        const int rl = lane & 15;
        s16x8 af[4], bfr[4];
#pragma unroll
        for (int mi = 0; mi < 4; mi++)
            af[mi] = *(const s16x8*)&As[(wm + mi * 16 + rl) * 32 + kq];
#pragma unroll
        for (int ni = 0; ni < 4; ni++)
            bfr[ni] = *(const s16x8*)&Bs[(wn + ni * 16 + rl) * 32 + kq];
#pragma unroll
        for (int mi = 0; mi < 4; mi++)
#pragma unroll
            for (int ni = 0; ni < 4; ni++)
                acc[mi][ni] = __builtin_amdgcn_mfma_f32_16x16x32_bf16(
                    af[mi], bfr[ni], acc[mi][ni], 0, 0, 0);
        __syncthreads();
    }

    const int cl = lane & 15;
    const int rq = (lane >> 4) * 4;
#pragma unroll
    for (int mi = 0; mi < 4; mi++)
#pragma unroll
        for (int ni = 0; ni < 4; ni++)
#pragma unroll
            for (int r = 0; r < 4; r++) {
                int row = bm + wm + mi * 16 + rq + r;
                int col = bn + wn + ni * 16 + cl;
                if (Cb) Cb[(size_t)row * N + col] = f2b(acc[mi][ni][r]);
                else    Cf[(size_t)row * N + col] = acc[mi][ni][r];
            }
}

// ---------------- small utility kernels ----------------
// fp32 -> bf16 pad copy
__global__ void pad_copy_kernel(const float* __restrict__ src,
                                unsigned short* __restrict__ dst,
                                int valid_rows, int cols, long total)
{
    long idx = (long)blockIdx.x * blockDim.x + threadIdx.x;
    if (idx >= total) return;
    int n = (int)(idx / cols);
    dst[idx] = (n < valid_rows) ? f2b(src[idx]) : (unsigned short)0;
}

__global__ void deg_init_kernel(float* deg) {
    int i = blockIdx.x * blockDim.x + threadIdx.x;
    if (i < NNODES) deg[i] = 1.0f;   // self loop
}
__global__ void deg_count_kernel(const int* __restrict__ ei, float* deg) {
    int e = blockIdx.x * blockDim.x + threadIdx.x;
    if (e < NEDGES) atomicAdd(&deg[ei[NEDGES + e]], 1.0f);
}
__global__ void dinv_kernel(const float* __restrict__ deg, float* dinv) {
    int i = blockIdx.x * blockDim.x + threadIdx.x;
    if (i < NNODES) dinv[i] = rsqrtf(deg[i]);
}

// pack CGConv weights (fp32 -> bf16): out[j,k] = BT for GEMM, j=0..2047,k=0..511
__global__ void pack_cgw_kernel(const float* __restrict__ Wf,
                                const float* __restrict__ Ws,
                                unsigned short* __restrict__ out)
{
    int idx = blockIdx.x * blockDim.x + threadIdx.x;
    if (idx >= 2048 * 512) return;
    int j = idx >> 9;
    int k = idx & 511;
    float v;
    if (j < 512)       v = Wf[(size_t)k * 512 + j];                    // dst part
    else if (j < 1024) v = Wf[(size_t)(512 + k) * 512 + (j - 512)];    // src part
    else if (j < 1536) v = Ws[(size_t)k * 512 + (j - 1024)];
    else               v = Ws[(size_t)(512 + k) * 512 + (j - 1536)];
    out[idx] = f2b(v);
}

// transpose W[K,Nout] (fp32) -> WT[Nout,K] (bf16)
__global__ void pack_t_kernel(const float* __restrict__ W,
                              unsigned short* __restrict__ WT,
                              int K, int Nout)
{
    long idx = (long)blockIdx.x * blockDim.x + threadIdx.x;
    if (idx >= (long)K * Nout) return;
    int j = (int)(idx / K);
    int k = (int)(idx % K);
    WT[idx] = f2b(W[(size_t)k * Nout + j]);
}

// ---------------- CGConv edge kernel ----------------
// P (bf16) [n, 0:512]=f_dst  [512:1024]=f_src  [1024:1536]=s_dst  [1536:2048]=s_src
__global__ __launch_bounds__(256) void cg_edge_kernel(
    const unsigned short* __restrict__ P,
    const int* __restrict__ ei,
    const float* __restrict__ ea,        // [E,16] fp32
    const float* __restrict__ Wf,        // [1040,512] fp32, rows 1024.. are W_e
    const float* __restrict__ Ws,
    const float* __restrict__ bfv,
    const float* __restrict__ bsv,
    float* __restrict__ agg)
{
    const int tid = threadIdx.x;
    const int c0  = tid * 2;
    float wf0[16], wf1[16], ws0[16], ws1[16];
#pragma unroll
    for (int k = 0; k < 16; k++) {
        const size_t rb = (size_t)(1024 + k) * 512;
        wf0[k] = Wf[rb + c0];
        wf1[k] = Wf[rb + c0 + 1];
        ws0[k] = Ws[rb + c0];
        ws1[k] = Ws[rb + c0 + 1];
    }
    const float bF0 = bfv[c0], bF1 = bfv[c0 + 1];
    const float bS0 = bsv[c0], bS1 = bsv[c0 + 1];

    for (int e = blockIdx.x; e < NEDGES; e += gridDim.x) {
        const int src = ei[e];
        const int dst = ei[NEDGES + e];
        float ek[16];
        const float4* ep = (const float4*)(ea + (size_t)e * 16);
#pragma unroll
        for (int q = 0; q < 4; q++) {
            float4 v = ep[q];
            ek[q * 4 + 0] = v.x; ek[q * 4 + 1] = v.y;
            ek[q * 4 + 2] = v.z; ek[q * 4 + 3] = v.w;
        }
        const unsigned short* Pd = P + (size_t)dst * 2048;
        const unsigned short* Ps = P + (size_t)src * 2048;
        unsigned int fd = *(const unsigned int*)(Pd + c0);
        unsigned int fs = *(const unsigned int*)(Ps + 512 + c0);
        unsigned int sd = *(const unsigned int*)(Pd + 1024 + c0);
        unsigned int ss = *(const unsigned int*)(Ps + 1536 + c0);
        float f0 = b2f((unsigned short)fd) + b2f((unsigned short)fs) + bF0;
        float f1 = b2f((unsigned short)(fd >> 16)) + b2f((unsigned short)(fs >> 16)) + bF1;
        float s0 = b2f((unsigned short)sd) + b2f((unsigned short)ss) + bS0;
        float s1 = b2f((unsigned short)(sd >> 16)) + b2f((unsigned short)(ss >> 16)) + bS1;
#pragma unroll
        for (int k = 0; k < 16; k++) {
            f0 = fmaf(ek[k], wf0[k], f0);
            f1 = fmaf(ek[k], wf1[k], f1);
            s0 = fmaf(ek[k], ws0[k], s0);
            s1 = fmaf(ek[k], ws1[k], s1);
        }
        float m0 = sigm(f0) * softp(s0);
        float m1 = sigm(f1) * softp(s1);
        float* ap = agg + (size_t)dst * 512 + c0;
        atomicAdd(ap,     m0);
        atomicAdd(ap + 1, m1);
    }
}

// BN(eval) + residual + ReLU -> bf16 (zero pad rows)
// residual: fp32 (xresf, [NNODES,512]) if non-null, else bf16 (xresb, [NPAD,512])
__global__ void cg_combine_kernel(const float* __restrict__ agg,
                                  const float* __restrict__ xresf,
                                  const unsigned short* __restrict__ xresb,
                                  const float* __restrict__ g,
                                  const float* __restrict__ be,
                                  unsigned short* __restrict__ hout)
{
    long idx = (long)blockIdx.x * blockDim.x + threadIdx.x;
    if (idx >= (long)NPAD * 512) return;
    int n = (int)(idx >> 9);
    int c = (int)(idx & 511);
    if (n < NNODES) {
        float res = xresf ? xresf[(size_t)n * 512 + c] : b2f(xresb[idx]);
        float scale = g[c] * rsqrtf(1.f + 1e-5f);
        float v = agg[idx] * scale + be[c] + res;
        hout[idx] = f2b(fmaxf(v, 0.f));
    } else {
        hout[idx] = 0;
    }
}

// ---------------- GCN ----------------
__global__ __launch_bounds__(256) void gcn_edge_kernel(
    const float* __restrict__ pre,  // [NPAD,256] fp32
    const int* __restrict__ ei,
    const float* __restrict__ dinv,
    float* __restrict__ agg)
{
    const int lane = threadIdx.x & 63;
    const int wid  = threadIdx.x >> 6;
    const int c0   = lane * 4;
    for (int e = blockIdx.x * 4 + wid; e < NEDGES; e += gridDim.x * 4) {
        int src = ei[e], dst = ei[NEDGES + e];
        float w = dinv[src] * dinv[dst];
        const float4 v = *(const float4*)(pre + (size_t)src * 256 + c0);
        float* ap = agg + (size_t)dst * 256 + c0;
        atomicAdd(ap + 0, w * v.x);
        atomicAdd(ap + 1, w * v.y);
        atomicAdd(ap + 2, w * v.z);
        atomicAdd(ap + 3, w * v.w);
    }
}

// combine; hout = bf16 staging for next GEMM; doutf (fp32, [NNODES,256]) = final h output
__global__ void gcn_combine_kernel(const float* __restrict__ agg,
                                   const float* __restrict__ pre,
                                   const float* __restrict__ dinv,
                                   const float* __restrict__ b,
                                   unsigned short* __restrict__ hout,
                                   float* __restrict__ doutf)
{
    long idx = (long)blockIdx.x * blockDim.x + threadIdx.x;
    if (idx >= (long)NPAD * 256) return;
    int n = (int)(idx >> 8);
    int c = (int)(idx & 255);
    if (n < NNODES) {
        float di = dinv[n];
        float v = fmaxf(agg[idx] + di * di * pre[idx] + b[c], 0.f);
        hout[idx] = f2b(v);
        if (doutf) doutf[idx] = v;
    } else {
        hout[idx] = 0;
    }
}

// ---------------- MLP ----------------
__global__ void build_zc_kernel(const unsigned short* __restrict__ h4,
                                const float* __restrict__ goal,
                                unsigned short* __restrict__ zc)
{
    long idx = (long)blockIdx.x * blockDim.x + threadIdx.x;
    if (idx >= (long)NPAD * 768) return;
    int n = (int)(idx / 768);
    int c = (int)(idx % 768);
    unsigned short v = 0;
    if (n < NNODES)
        v = (c < 256) ? h4[(size_t)n * 256 + c]
                      : f2b(goal[(size_t)n * 512 + (c - 256)]);
    zc[idx] = v;
}

__global__ void mlp_epi_kernel(const float* __restrict__ Cm,
                               const float* __restrict__ bd1,
                               unsigned short* __restrict__ t)
{
    long idx = (long)blockIdx.x * blockDim.x + threadIdx.x;
    if (idx >= (long)NNODES * 512) return;
    int c = (int)(idx & 511);
    t[idx] = f2b(fmaxf(Cm[idx] + bd1[c], 0.f));
}

__global__ __launch_bounds__(256) void final_dot_kernel(
    const unsigned short* __restrict__ t,
    const float* __restrict__ Wd2,
    const float* __restrict__ bd2,
    float* __restrict__ pred)
{
    const int lane = threadIdx.x & 63;
    const int wid  = threadIdx.x >> 6;
    float w[8];
#pragma unroll
    for (int i = 0; i < 8; i++) w[i] = Wd2[lane * 8 + i];
    const float bd = bd2[0];
    for (int n = blockIdx.x * 4 + wid; n < NNODES; n += gridDim.x * 4) {
        const unsigned short* tp = t + (size_t)n * 512 + lane * 8;
        float s = 0.f;
#pragma unroll
        for (int i = 0; i < 8; i++) s = fmaf(b2f(tp[i]), w[i], s);
#pragma unroll
        for (int off = 32; off; off >>= 1) s += __shfl_xor(s, off, 64);
        if (lane == 0) pred[n] = s + bd;
    }
}

// ---------------- launcher ----------------
extern "C" void kernel_launch(void* const* d_in, const int* in_sizes, int n_in,
                              void* d_out, int out_size, void* d_ws, size_t ws_size,
                              hipStream_t stream)
{
    (void)in_sizes; (void)n_in; (void)out_size; (void)ws_size;
    const float* x    = (const float*)d_in[0];
    const int*   ei   = (const int*)d_in[1];
    const float* ea   = (const float*)d_in[2];
    const float* goal = (const float*)d_in[3];
    const float* Wf1  = (const float*)d_in[4];
    const float* bf1  = (const float*)d_in[5];
    const float* Ws1  = (const float*)d_in[6];
    const float* bs1  = (const float*)d_in[7];
    const float* g1   = (const float*)d_in[8];
    const float* be1  = (const float*)d_in[9];
    const float* Wf2  = (const float*)d_in[10];
    const float* bf2  = (const float*)d_in[11];
    const float* Ws2  = (const float*)d_in[12];
    const float* bs2  = (const float*)d_in[13];
    const float* g2   = (const float*)d_in[14];
    const float* be2  = (const float*)d_in[15];
    const float* W3   = (const float*)d_in[16];
    const float* b3   = (const float*)d_in[17];
    const float* W4   = (const float*)d_in[18];
    const float* b4   = (const float*)d_in[19];
    const float* Wd1  = (const float*)d_in[20];
    const float* bd1  = (const float*)d_in[21];
    const float* Wd2  = (const float*)d_in[22];
    const float* bd2  = (const float*)d_in[23];
    float* outp = (float*)d_out;   // fp32 output: [0..N) pred, [N..N+N*256) h

    // ---- workspace layout (~187.6 MB) ----
    char* ws = (char*)d_ws;
    size_t off = 0;
    auto alloc = [&](size_t bytes) -> char* {
        char* p = ws + off;
        off += (bytes + 255) & ~(size_t)255;
        return p;
    };
    unsigned short* P     = (unsigned short*)alloc((size_t)NPAD * 2048 * 2); // later zc + tb
    float*          agg   = (float*)alloc((size_t)NPAD * 512 * 4);           // later mlpC
    unsigned short* bufA  = (unsigned short*)alloc((size_t)NPAD * 512 * 2);  // xpad / h2 / h4
    unsigned short* bufB  = (unsigned short*)alloc((size_t)NPAD * 512 * 2);  // h1 / pre34 fp32
    unsigned short* bufC  = (unsigned short*)alloc((size_t)NPAD * 512 * 2);  // h3
    unsigned short* wpack = (unsigned short*)alloc((size_t)2048 * 512 * 2);
    float*          deg   = (float*)alloc((size_t)NNODES * 4);
    float*          dinv  = (float*)alloc((size_t)NNODES * 4);

    unsigned short* xpad  = bufA;
    unsigned short* h1    = bufB;
    unsigned short* h2    = bufA;
    float*          pre34 = (float*)bufB;
    unsigned short* h3    = bufC;
    unsigned short* h4    = bufA;
    unsigned short* zc    = P;                        // [NPAD,768] bf16
    unsigned short* tb    = P + (size_t)NPAD * 1024;  // past zc region
    float*          mlpC  = agg;

    const int B = 256;
    {
        long tot = (long)NPAD * 512;
        pad_copy_kernel<<<(unsigned)((tot + B - 1) / B), B, 0, stream>>>(x, xpad, NNODES, 512, tot);
    }
    deg_init_kernel<<<(NNODES + B - 1) / B, B, 0, stream>>>(deg);
    deg_count_kernel<<<(NEDGES + B - 1) / B, B, 0, stream>>>(ei, deg);
    dinv_kernel<<<(NNODES + B - 1) / B, B, 0, stream>>>(deg, dinv);

    dim3 gBig(NPAD / 128, 2048 / 128);

    // ---- CGConv layer 1 ----
    pack_cgw_kernel<<<(2048 * 512 + B - 1) / B, B, 0, stream>>>(Wf1, Ws1, wpack);
    gemm_bt_kernel<<<gBig, B, 0, stream>>>(xpad, wpack, nullptr, P, NPAD, 2048, 512);
    hipMemsetAsync(agg, 0, (size_t)NPAD * 512 * 4, stream);
    cg_edge_kernel<<<1280, B, 0, stream>>>(P, ei, ea, Wf1, Ws1, bf1, bs1, agg);
    cg_combine_kernel<<<(unsigned)(((long)NPAD * 512 + B - 1) / B), B, 0, stream>>>(
        agg, x, nullptr, g1, be1, h1);

    // ---- CGConv layer 2 ----
    pack_cgw_kernel<<<(2048 * 512 + B - 1) / B, B, 0, stream>>>(Wf2, Ws2, wpack);
    gemm_bt_kernel<<<gBig, B, 0, stream>>>(h1, wpack, nullptr, P, NPAD, 2048, 512);
    hipMemsetAsync(agg, 0, (size_t)NPAD * 512 * 4, stream);
    cg_edge_kernel<<<1280, B, 0, stream>>>(P, ei, ea, Wf2, Ws2, bf2, bs2, agg);
    cg_combine_kernel<<<(unsigned)(((long)NPAD * 512 + B - 1) / B), B, 0, stream>>>(
        agg, nullptr, h1, g2, be2, h2);

    // ---- GCN layer 3 ----
    pack_t_kernel<<<(256 * 512 + B - 1) / B, B, 0, stream>>>(W3, wpack, 512, 256);
    gemm_bt_kernel<<<dim3(NPAD / 128, 2), B, 0, stream>>>(h2, wpack, pre34, nullptr, NPAD, 256, 512);
    hipMemsetAsync(agg, 0, (size_t)NPAD * 256 * 4, stream);
    gcn_edge_kernel<<<2048, B, 0, stream>>>(pre34, ei, dinv, agg);
    gcn_combine_kernel<<<(unsigned)(((long)NPAD * 256 + B - 1) / B), B, 0, stream>>>(
        agg, pre34, dinv, b3, h3, (float*)nullptr);

    // ---- GCN layer 4 ----
    pack_t_kernel<<<(256 * 256 + B - 1) / B, B, 0, stream>>>(W4, wpack, 256, 256);
    gemm_bt_kernel<<<dim3(NPAD / 128, 2), B, 0, stream>>>(h3, wpack, pre34, nullptr, NPAD, 256, 256);
    hipMemsetAsync(agg, 0, (size_t)NPAD * 256 * 4, stream);
    gcn_edge_kernel<<<2048, B, 0, stream>>>(pre34, ei, dinv, agg);
    gcn_combine_kernel<<<(unsigned)(((long)NPAD * 256 + B - 1) / B), B, 0, stream>>>(
        agg, pre34, dinv, b4, h4, outp + NNODES);   // fp32 h output

    // ---- distance MLP ----
    build_zc_kernel<<<(unsigned)(((long)NPAD * 768 + B - 1) / B), B, 0, stream>>>(h4, goal, zc);
    pack_t_kernel<<<(512 * 768 + B - 1) / B, B, 0, stream>>>(Wd1, wpack, 768, 512);
    gemm_bt_kernel<<<dim3(NPAD / 128, 4), B, 0, stream>>>(zc, wpack, mlpC, nullptr, NPAD, 512, 768);
    mlp_epi_kernel<<<(unsigned)(((long)NNODES * 512 + B - 1) / B), B, 0, stream>>>(mlpC, bd1, tb);
    final_dot_kernel<<<512, B, 0, stream>>>(tb, Wd2, bd2, outp);   // fp32 pred
}

// Round 6
// 922.924 us; speedup vs baseline: 2.9457x; 2.9457x over previous
//
#include <hip/hip_runtime.h>
#include <stdint.h>

#define NNODES 20000
#define NEDGES 160000
#define NPAD   20096   // 157 * 128

typedef float f32x4 __attribute__((ext_vector_type(4)));
typedef short s16x8 __attribute__((ext_vector_type(8)));

__device__ __forceinline__ float b2f(unsigned short b) {
    unsigned int u = ((unsigned int)b) << 16;
    return __builtin_bit_cast(float, u);
}
__device__ __forceinline__ unsigned short f2b(float f) {
    unsigned int u = __builtin_bit_cast(unsigned int, f);
    unsigned int r = (u + 0x7FFFu + ((u >> 16) & 1u)) >> 16;
    return (unsigned short)r;
}
__device__ __forceinline__ float sigm(float x) {
    return 1.0f / (1.0f + __expf(-x));
}
__device__ __forceinline__ float softp(float x) {
    return fmaxf(x, 0.f) + __logf(1.f + __expf(-fabsf(x)));
}

// ---- GEMM: C[M,N] = A[M,K](bf16) @ BT[N,K]^T(bf16); C fp32 or bf16 ----
__global__ __launch_bounds__(256) void gemm_bt_kernel(
    const unsigned short* __restrict__ A,
    const unsigned short* __restrict__ BT,
    float* __restrict__ Cf,
    unsigned short* __restrict__ Cb,
    int M, int N, int K)
{
    __shared__ unsigned short As[128 * 32];
    __shared__ unsigned short Bs[128 * 32];
    const int tid  = threadIdx.x;
    const int wid  = tid >> 6;
    const int lane = tid & 63;
    const int bm = blockIdx.x * 128;
    const int bn = blockIdx.y * 128;
    const int wm = (wid & 1) * 64;
    const int wn = (wid >> 1) * 64;

    f32x4 acc[4][4];
#pragma unroll
    for (int i = 0; i < 4; i++)
#pragma unroll
        for (int j = 0; j < 4; j++) acc[i][j] = {0.f, 0.f, 0.f, 0.f};

    for (int k0 = 0; k0 < K; k0 += 32) {
#pragma unroll
        for (int r = 0; r < 2; r++) {
            int flat = r * 256 + tid;
            int row  = flat >> 2;
            int part = flat & 3;
            const unsigned short* ga = A  + (size_t)(bm + row) * K + k0 + part * 8;
            const unsigned short* gb = BT + (size_t)(bn + row) * K + k0 + part * 8;
            __builtin_amdgcn_global_load_lds(
                (const __attribute__((address_space(1))) unsigned int*)ga,
                (__attribute__((address_space(3))) unsigned int*)&As[flat * 8], 16, 0, 0);
            __builtin_amdgcn_global_load_lds(
                (const __attribute__((address_space(1))) unsigned int*)gb,
                (__attribute__((address_space(3))) unsigned int*)&Bs[flat * 8], 16, 0, 0);
        }
        __syncthreads();

        const int kq = (lane >> 4) * 8;
        const int rl = lane & 15;
        s16x8 af[4], bfr[4];
#pragma unroll
        for (int mi = 0; mi < 4; mi++)
            af[mi] = *(const s16x8*)&As[(wm + mi * 16 + rl) * 32 + kq];
#pragma unroll
        for (int ni = 0; ni < 4; ni++)
            bfr[ni] = *(const s16x8*)&Bs[(wn + ni * 16 + rl) * 32 + kq];
#pragma unroll
        for (int mi = 0; mi < 4; mi++)
#pragma unroll
            for (int ni = 0; ni < 4; ni++)
                acc[mi][ni] = __builtin_amdgcn_mfma_f32_16x16x32_bf16(
                    af[mi], bfr[ni], acc[mi][ni], 0, 0, 0);
        __syncthreads();
    }

    const int cl = lane & 15;
    const int rq = (lane >> 4) * 4;
#pragma unroll
    for (int mi = 0; mi < 4; mi++)
#pragma unroll
        for (int ni = 0; ni < 4; ni++)
#pragma unroll
            for (int r = 0; r < 4; r++) {
                int row = bm + wm + mi * 16 + rq + r;
                int col = bn + wn + ni * 16 + cl;
                if (Cb) Cb[(size_t)row * N + col] = f2b(acc[mi][ni][r]);
                else    Cf[(size_t)row * N + col] = acc[mi][ni][r];
            }
}

// ---------------- CSR build ----------------
__global__ void count_kernel(const int* __restrict__ ei, int* __restrict__ counts) {
    int e = blockIdx.x * blockDim.x + threadIdx.x;
    if (e < NEDGES) atomicAdd(&counts[ei[NEDGES + e]], 1);
}

// exclusive scan of counts[0..NNODES) -> row_ptr[0..NNODES], single block 1024 thr
__global__ __launch_bounds__(1024) void scan_kernel(const int* __restrict__ counts,
                                                    int* __restrict__ row_ptr)
{
    __shared__ int sdata[1024];
    const int t = threadIdx.x;
    int vals[20];
    const int base = t * 20;
    int lsum = 0;
#pragma unroll
    for (int j = 0; j < 20; j++) {
        int idx = base + j;
        int v = (idx < NNODES) ? counts[idx] : 0;
        vals[j] = v; lsum += v;
    }
    sdata[t] = lsum;
    __syncthreads();
    for (int off = 1; off < 1024; off <<= 1) {
        int v = (t >= off) ? sdata[t - off] : 0;
        __syncthreads();
        sdata[t] += v;
        __syncthreads();
    }
    int run = sdata[t] - lsum;
#pragma unroll
    for (int j = 0; j < 20; j++) {
        int idx = base + j;
        if (idx < NNODES) row_ptr[idx] = run;
        run += vals[j];
    }
    if (t == 1023) row_ptr[NNODES] = sdata[1023];
}

__global__ void fill_kernel(const int* __restrict__ ei,
                            const int* __restrict__ row_ptr,
                            int* __restrict__ cursor,
                            int* __restrict__ csr_src,
                            int* __restrict__ csr_eid)
{
    int e = blockIdx.x * blockDim.x + threadIdx.x;
    if (e >= NEDGES) return;
    int dst = ei[NEDGES + e];
    int p = row_ptr[dst] + atomicAdd(&cursor[dst], 1);
    csr_src[p] = ei[e];
    csr_eid[p] = e;
}

__global__ void dinv_kernel(const int* __restrict__ row_ptr, float* __restrict__ dinv) {
    int i = blockIdx.x * blockDim.x + threadIdx.x;
    if (i < NNODES) {
        int deg = row_ptr[i + 1] - row_ptr[i] + 1;   // + self loop
        dinv[i] = rsqrtf((float)deg);
    }
}

// ---------------- packing ----------------
__global__ void pad_copy_kernel(const float* __restrict__ src,
                                unsigned short* __restrict__ dst,
                                int valid_rows, int cols, long total)
{
    long idx = (long)blockIdx.x * blockDim.x + threadIdx.x;
    if (idx >= total) return;
    int n = (int)(idx / cols);
    dst[idx] = (n < valid_rows) ? f2b(src[idx]) : (unsigned short)0;
}

__global__ void pack_cgw_kernel(const float* __restrict__ Wf,
                                const float* __restrict__ Ws,
                                unsigned short* __restrict__ out)
{
    int idx = blockIdx.x * blockDim.x + threadIdx.x;
    if (idx >= 2048 * 512) return;
    int j = idx >> 9;
    int k = idx & 511;
    float v;
    if (j < 512)       v = Wf[(size_t)k * 512 + j];
    else if (j < 1024) v = Wf[(size_t)(512 + k) * 512 + (j - 512)];
    else if (j < 1536) v = Ws[(size_t)k * 512 + (j - 1024)];
    else               v = Ws[(size_t)(512 + k) * 512 + (j - 1536)];
    out[idx] = f2b(v);
}

__global__ void pack_t_kernel(const float* __restrict__ W,
                              unsigned short* __restrict__ WT,
                              int K, int Nout)
{
    long idx = (long)blockIdx.x * blockDim.x + threadIdx.x;
    if (idx >= (long)K * Nout) return;
    int j = (int)(idx / K);
    int k = (int)(idx % K);
    WT[idx] = f2b(W[(size_t)k * Nout + j]);
}

// ---------------- CGConv gather (atomic-free, fused combine) ----------------
// P (bf16) [n,0:512]=f_dst [512:1024]=f_src [1024:1536]=s_dst [1536:2048]=s_src
// One block per node row (NPAD blocks); 256 threads, 2 channels each.
__global__ __launch_bounds__(256) void cg_gather_kernel(
    const unsigned short* __restrict__ P,
    const int* __restrict__ row_ptr,
    const int* __restrict__ csr_src,
    const int* __restrict__ csr_eid,
    const float* __restrict__ ea,
    const float* __restrict__ Wf,   // [1040,512], rows 1024.. = W_e
    const float* __restrict__ Ws,
    const float* __restrict__ bfv,
    const float* __restrict__ bsv,
    const float* __restrict__ g,
    const float* __restrict__ be,
    const float* __restrict__ xresf,          // fp32 [NNODES,512] or null
    const unsigned short* __restrict__ xresb, // bf16 [NPAD,512] or null
    unsigned short* __restrict__ hout)
{
    const int n   = blockIdx.x;
    const int tid = threadIdx.x;
    const int c0  = tid * 2;
    if (n >= NNODES) {
        *(unsigned int*)&hout[(size_t)n * 512 + c0] = 0;
        return;
    }
    float wf0[16], wf1[16], ws0[16], ws1[16];
#pragma unroll
    for (int k = 0; k < 16; k++) {
        const size_t rb = (size_t)(1024 + k) * 512;
        wf0[k] = Wf[rb + c0];
        wf1[k] = Wf[rb + c0 + 1];
        ws0[k] = Ws[rb + c0];
        ws1[k] = Ws[rb + c0 + 1];
    }
    const unsigned short* Pd = P + (size_t)n * 2048;
    unsigned int fd = *(const unsigned int*)(Pd + c0);
    unsigned int sd = *(const unsigned int*)(Pd + 1024 + c0);
    const float baseF0 = b2f((unsigned short)fd) + bfv[c0];
    const float baseF1 = b2f((unsigned short)(fd >> 16)) + bfv[c0 + 1];
    const float baseS0 = b2f((unsigned short)sd) + bsv[c0];
    const float baseS1 = b2f((unsigned short)(sd >> 16)) + bsv[c0 + 1];

    float acc0 = 0.f, acc1 = 0.f;
    const int i0 = row_ptr[n], i1 = row_ptr[n + 1];
    for (int i = i0; i < i1; i++) {
        const int src = csr_src[i];
        const int e   = csr_eid[i];
        float ek[16];
        const float4* ep = (const float4*)(ea + (size_t)e * 16);
#pragma unroll
        for (int q = 0; q < 4; q++) {
            float4 v = ep[q];
            ek[q * 4 + 0] = v.x; ek[q * 4 + 1] = v.y;
            ek[q * 4 + 2] = v.z; ek[q * 4 + 3] = v.w;
        }
        const unsigned short* Ps = P + (size_t)src * 2048;
        unsigned int fs = *(const unsigned int*)(Ps + 512 + c0);
        unsigned int ss = *(const unsigned int*)(Ps + 1536 + c0);
        float f0 = baseF0 + b2f((unsigned short)fs);
        float f1 = baseF1 + b2f((unsigned short)(fs >> 16));
        float s0 = baseS0 + b2f((unsigned short)ss);
        float s1 = baseS1 + b2f((unsigned short)(ss >> 16));
#pragma unroll
        for (int k = 0; k < 16; k++) {
            f0 = fmaf(ek[k], wf0[k], f0);
            f1 = fmaf(ek[k], wf1[k], f1);
            s0 = fmaf(ek[k], ws0[k], s0);
            s1 = fmaf(ek[k], ws1[k], s1);
        }
        acc0 += sigm(f0) * softp(s0);
        acc1 += sigm(f1) * softp(s1);
    }
    // fused BN(eval) + residual + ReLU
    const float rs = rsqrtf(1.f + 1e-5f);
    float res0, res1;
    if (xresf) {
        res0 = xresf[(size_t)n * 512 + c0];
        res1 = xresf[(size_t)n * 512 + c0 + 1];
    } else {
        unsigned int r = *(const unsigned int*)&xresb[(size_t)n * 512 + c0];
        res0 = b2f((unsigned short)r);
        res1 = b2f((unsigned short)(r >> 16));
    }
    float v0 = fmaxf(acc0 * (g[c0] * rs) + be[c0] + res0, 0.f);
    float v1 = fmaxf(acc1 * (g[c0 + 1] * rs) + be[c0 + 1] + res1, 0.f);
    unsigned int packed = (unsigned int)f2b(v0) | ((unsigned int)f2b(v1) << 16);
    *(unsigned int*)&hout[(size_t)n * 512 + c0] = packed;
}

// ---------------- GCN gather (atomic-free, fused combine) ----------------
// One block per node row (NPAD blocks); 256 threads, 1 channel each.
__global__ __launch_bounds__(256) void gcn_gather_kernel(
    const float* __restrict__ pre,   // [NPAD,256] fp32
    const int* __restrict__ row_ptr,
    const int* __restrict__ csr_src,
    const float* __restrict__ dinv,
    const float* __restrict__ b,
    unsigned short* __restrict__ hout,  // bf16 [NPAD,256]
    float* __restrict__ doutf)          // fp32 [NNODES,256] or null
{
    const int n = blockIdx.x;
    const int c = threadIdx.x;
    if (n >= NNODES) {
        hout[(size_t)n * 256 + c] = 0;
        return;
    }
    const float din = dinv[n];
    float acc = 0.f;
    const int i0 = row_ptr[n], i1 = row_ptr[n + 1];
    for (int i = i0; i < i1; i++) {
        const int src = csr_src[i];
        acc = fmaf(dinv[src], pre[(size_t)src * 256 + c], acc);
    }
    float v = fmaxf(acc * din + din * din * pre[(size_t)n * 256 + c] + b[c], 0.f);
    hout[(size_t)n * 256 + c] = f2b(v);
    if (doutf) doutf[(size_t)n * 256 + c] = v;
}

// ---------------- MLP ----------------
__global__ void build_zc_kernel(const unsigned short* __restrict__ h4,
                                const float* __restrict__ goal,
                                unsigned short* __restrict__ zc)
{
    long idx = (long)blockIdx.x * blockDim.x + threadIdx.x;
    if (idx >= (long)NPAD * 768) return;
    int n = (int)(idx / 768);
    int c = (int)(idx % 768);
    unsigned short v = 0;
    if (n < NNODES)
        v = (c < 256) ? h4[(size_t)n * 256 + c]
                      : f2b(goal[(size_t)n * 512 + (c - 256)]);
    zc[idx] = v;
}

__global__ void mlp_epi_kernel(const float* __restrict__ Cm,
                               const float* __restrict__ bd1,
                               unsigned short* __restrict__ t)
{
    long idx = (long)blockIdx.x * blockDim.x + threadIdx.x;
    if (idx >= (long)NNODES * 512) return;
    int c = (int)(idx & 511);
    t[idx] = f2b(fmaxf(Cm[idx] + bd1[c], 0.f));
}

__global__ __launch_bounds__(256) void final_dot_kernel(
    const unsigned short* __restrict__ t,
    const float* __restrict__ Wd2,
    const float* __restrict__ bd2,
    float* __restrict__ pred)
{
    const int lane = threadIdx.x & 63;
    const int wid  = threadIdx.x >> 6;
    float w[8];
#pragma unroll
    for (int i = 0; i < 8; i++) w[i] = Wd2[lane * 8 + i];
    const float bd = bd2[0];
    for (int n = blockIdx.x * 4 + wid; n < NNODES; n += gridDim.x * 4) {
        const unsigned short* tp = t + (size_t)n * 512 + lane * 8;
        float s = 0.f;
#pragma unroll
        for (int i = 0; i < 8; i++) s = fmaf(b2f(tp[i]), w[i], s);
#pragma unroll
        for (int off = 32; off; off >>= 1) s += __shfl_xor(s, off, 64);
        if (lane == 0) pred[n] = s + bd;
    }
}

// ---------------- launcher ----------------
extern "C" void kernel_launch(void* const* d_in, const int* in_sizes, int n_in,
                              void* d_out, int out_size, void* d_ws, size_t ws_size,
                              hipStream_t stream)
{
    (void)in_sizes; (void)n_in; (void)out_size; (void)ws_size;
    const float* x    = (const float*)d_in[0];
    const int*   ei   = (const int*)d_in[1];
    const float* ea   = (const float*)d_in[2];
    const float* goal = (const float*)d_in[3];
    const float* Wf1  = (const float*)d_in[4];
    const float* bf1  = (const float*)d_in[5];
    const float* Ws1  = (const float*)d_in[6];
    const float* bs1  = (const float*)d_in[7];
    const float* g1   = (const float*)d_in[8];
    const float* be1  = (const float*)d_in[9];
    const float* Wf2  = (const float*)d_in[10];
    const float* bf2  = (const float*)d_in[11];
    const float* Ws2  = (const float*)d_in[12];
    const float* bs2  = (const float*)d_in[13];
    const float* g2   = (const float*)d_in[14];
    const float* be2  = (const float*)d_in[15];
    const float* W3   = (const float*)d_in[16];
    const float* b3   = (const float*)d_in[17];
    const float* W4   = (const float*)d_in[18];
    const float* b4   = (const float*)d_in[19];
    const float* Wd1  = (const float*)d_in[20];
    const float* bd1  = (const float*)d_in[21];
    const float* Wd2  = (const float*)d_in[22];
    const float* bd2  = (const float*)d_in[23];
    float* outp = (float*)d_out;   // fp32: [0..N) pred, [N..N+N*256) h

    char* ws = (char*)d_ws;
    size_t off = 0;
    auto alloc = [&](size_t bytes) -> char* {
        char* p = ws + off;
        off += (bytes + 255) & ~(size_t)255;
        return p;
    };
    unsigned short* P     = (unsigned short*)alloc((size_t)NPAD * 2048 * 2); // later zc + tb
    float*          mlpC  = (float*)alloc((size_t)NPAD * 512 * 4);
    unsigned short* bufA  = (unsigned short*)alloc((size_t)NPAD * 512 * 2);  // xpad / h2 / h4
    unsigned short* bufB  = (unsigned short*)alloc((size_t)NPAD * 512 * 2);  // h1 / pre34 fp32
    unsigned short* bufC  = (unsigned short*)alloc((size_t)NPAD * 512 * 2);  // h3
    unsigned short* wpack = (unsigned short*)alloc((size_t)2048 * 512 * 2);
    int*            counts  = (int*)alloc((size_t)NNODES * 4);
    int*            row_ptr = (int*)alloc((size_t)(NNODES + 1) * 4);
    int*            csr_src = (int*)alloc((size_t)NEDGES * 4);
    int*            csr_eid = (int*)alloc((size_t)NEDGES * 4);
    float*          dinv    = (float*)alloc((size_t)NNODES * 4);

    unsigned short* xpad  = bufA;
    unsigned short* h1    = bufB;
    unsigned short* h2    = bufA;
    float*          pre34 = (float*)bufB;
    unsigned short* h3    = bufC;
    unsigned short* h4    = bufA;
    unsigned short* zc    = P;
    unsigned short* tb    = P + (size_t)NPAD * 1024;

    const int B = 256;

    // ---- CSR build (by destination) + dinv ----
    hipMemsetAsync(counts, 0, (size_t)NNODES * 4, stream);
    count_kernel<<<(NEDGES + B - 1) / B, B, 0, stream>>>(ei, counts);
    scan_kernel<<<1, 1024, 0, stream>>>(counts, row_ptr);
    hipMemsetAsync(counts, 0, (size_t)NNODES * 4, stream);
    fill_kernel<<<(NEDGES + B - 1) / B, B, 0, stream>>>(ei, row_ptr, counts, csr_src, csr_eid);
    dinv_kernel<<<(NNODES + B - 1) / B, B, 0, stream>>>(row_ptr, dinv);

    {
        long tot = (long)NPAD * 512;
        pad_copy_kernel<<<(unsigned)((tot + B - 1) / B), B, 0, stream>>>(x, xpad, NNODES, 512, tot);
    }

    dim3 gBig(NPAD / 128, 2048 / 128);

    // ---- CGConv layer 1 ----
    pack_cgw_kernel<<<(2048 * 512 + B - 1) / B, B, 0, stream>>>(Wf1, Ws1, wpack);
    gemm_bt_kernel<<<gBig, B, 0, stream>>>(xpad, wpack, nullptr, P, NPAD, 2048, 512);
    cg_gather_kernel<<<NPAD, B, 0, stream>>>(P, row_ptr, csr_src, csr_eid, ea,
                                             Wf1, Ws1, bf1, bs1, g1, be1,
                                             x, nullptr, h1);

    // ---- CGConv layer 2 ----
    pack_cgw_kernel<<<(2048 * 512 + B - 1) / B, B, 0, stream>>>(Wf2, Ws2, wpack);
    gemm_bt_kernel<<<gBig, B, 0, stream>>>(h1, wpack, nullptr, P, NPAD, 2048, 512);
    cg_gather_kernel<<<NPAD, B, 0, stream>>>(P, row_ptr, csr_src, csr_eid, ea,
                                             Wf2, Ws2, bf2, bs2, g2, be2,
                                             nullptr, h1, h2);

    // ---- GCN layer 3 ----
    pack_t_kernel<<<(256 * 512 + B - 1) / B, B, 0, stream>>>(W3, wpack, 512, 256);
    gemm_bt_kernel<<<dim3(NPAD / 128, 2), B, 0, stream>>>(h2, wpack, pre34, nullptr, NPAD, 256, 512);
    gcn_gather_kernel<<<NPAD, B, 0, stream>>>(pre34, row_ptr, csr_src, dinv, b3, h3, (float*)nullptr);

    // ---- GCN layer 4 ----
    pack_t_kernel<<<(256 * 256 + B - 1) / B, B, 0, stream>>>(W4, wpack, 256, 256);
    gemm_bt_kernel<<<dim3(NPAD / 128, 2), B, 0, stream>>>(h3, wpack, pre34, nullptr, NPAD, 256, 256);
    gcn_gather_kernel<<<NPAD, B, 0, stream>>>(pre34, row_ptr, csr_src, dinv, b4, h4, outp + NNODES);

    // ---- distance MLP ----
    build_zc_kernel<<<(unsigned)(((long)NPAD * 768 + B - 1) / B), B, 0, stream>>>(h4, goal, zc);
    pack_t_kernel<<<(512 * 768 + B - 1) / B, B, 0, stream>>>(Wd1, wpack, 768, 512);
    gemm_bt_kernel<<<dim3(NPAD / 128, 4), B, 0, stream>>>(zc, wpack, mlpC, nullptr, NPAD, 512, 768);
    mlp_epi_kernel<<<(unsigned)(((long)NNODES * 512 + B - 1) / B), B, 0, stream>>>(mlpC, bd1, tb);
    final_dot_kernel<<<512, B, 0, stream>>>(tb, Wd2, bd2, outp);
}

// Round 7
// 878.036 us; speedup vs baseline: 3.0963x; 1.0511x over previous
//
#include <hip/hip_runtime.h>
#include <stdint.h>

#define NNODES 20000
#define NEDGES 160000
#define NPAD   20096   // 157 * 128

typedef float f32x4 __attribute__((ext_vector_type(4)));
typedef float f32x2 __attribute__((ext_vector_type(2)));
typedef short s16x8 __attribute__((ext_vector_type(8)));

__device__ __forceinline__ float b2f(unsigned short b) {
    unsigned int u = ((unsigned int)b) << 16;
    return __builtin_bit_cast(float, u);
}
__device__ __forceinline__ unsigned short f2b(float f) {
    unsigned int u = __builtin_bit_cast(unsigned int, f);
    unsigned int r = (u + 0x7FFFu + ((u >> 16) & 1u)) >> 16;
    return (unsigned short)r;
}
// unpack 2 bf16 (packed in a dword) -> float2, 2 VALU ops
__device__ __forceinline__ f32x2 unpack2(unsigned int u) {
    f32x2 r;
    r.x = __builtin_bit_cast(float, u << 16);
    r.y = __builtin_bit_cast(float, u & 0xFFFF0000u);
    return r;
}

// ---- GEMM: C[M,N] = A[M,K](bf16) @ BT[N,K]^T(bf16); C fp32 or bf16 ----
// optional fused epilogue for bf16 path: v = relu(acc + bias[col])
__global__ __launch_bounds__(256) void gemm_bt_kernel(
    const unsigned short* __restrict__ A,
    const unsigned short* __restrict__ BT,
    float* __restrict__ Cf,
    unsigned short* __restrict__ Cb,
    int M, int N, int K,
    const float* __restrict__ bias)
{
    __shared__ unsigned short As[128 * 32];
    __shared__ unsigned short Bs[128 * 32];
    const int tid  = threadIdx.x;
    const int wid  = tid >> 6;
    const int lane = tid & 63;
    const int bm = blockIdx.x * 128;
    const int bn = blockIdx.y * 128;
    const int wm = (wid & 1) * 64;
    const int wn = (wid >> 1) * 64;

    f32x4 acc[4][4];
#pragma unroll
    for (int i = 0; i < 4; i++)
#pragma unroll
        for (int j = 0; j < 4; j++) acc[i][j] = {0.f, 0.f, 0.f, 0.f};

    for (int k0 = 0; k0 < K; k0 += 32) {
#pragma unroll
        for (int r = 0; r < 2; r++) {
            int flat = r * 256 + tid;
            int row  = flat >> 2;
            int part = flat & 3;
            const unsigned short* ga = A  + (size_t)(bm + row) * K + k0 + part * 8;
            const unsigned short* gb = BT + (size_t)(bn + row) * K + k0 + part * 8;
            __builtin_amdgcn_global_load_lds(
                (const __attribute__((address_space(1))) unsigned int*)ga,
                (__attribute__((address_space(3))) unsigned int*)&As[flat * 8], 16, 0, 0);
            __builtin_amdgcn_global_load_lds(
                (const __attribute__((address_space(1))) unsigned int*)gb,
                (__attribute__((address_space(3))) unsigned int*)&Bs[flat * 8], 16, 0, 0);
        }
        __syncthreads();

        const int kq = (lane >> 4) * 8;
        const int rl = lane & 15;
        s16x8 af[4], bfr[4];
#pragma unroll
        for (int mi = 0; mi < 4; mi++)
            af[mi] = *(const s16x8*)&As[(wm + mi * 16 + rl) * 32 + kq];
#pragma unroll
        for (int ni = 0; ni < 4; ni++)
            bfr[ni] = *(const s16x8*)&Bs[(wn + ni * 16 + rl) * 32 + kq];
#pragma unroll
        for (int mi = 0; mi < 4; mi++)
#pragma unroll
            for (int ni = 0; ni < 4; ni++)
                acc[mi][ni] = __builtin_amdgcn_mfma_f32_16x16x32_bf16(
                    af[mi], bfr[ni], acc[mi][ni], 0, 0, 0);
        __syncthreads();
    }

    const int cl = lane & 15;
    const int rq = (lane >> 4) * 4;
#pragma unroll
    for (int mi = 0; mi < 4; mi++)
#pragma unroll
        for (int ni = 0; ni < 4; ni++)
#pragma unroll
            for (int r = 0; r < 4; r++) {
                int row = bm + wm + mi * 16 + rq + r;
                int col = bn + wn + ni * 16 + cl;
                float v = acc[mi][ni][r];
                if (Cb) {
                    if (bias) v = fmaxf(v + bias[col], 0.f);
                    Cb[(size_t)row * N + col] = f2b(v);
                } else {
                    Cf[(size_t)row * N + col] = v;
                }
            }
}

// ---------------- CSR build ----------------
__global__ void count_kernel(const int* __restrict__ ei, int* __restrict__ counts) {
    int e = blockIdx.x * blockDim.x + threadIdx.x;
    if (e < NEDGES) atomicAdd(&counts[ei[NEDGES + e]], 1);
}

__global__ __launch_bounds__(1024) void scan_kernel(const int* __restrict__ counts,
                                                    int* __restrict__ row_ptr)
{
    __shared__ int sdata[1024];
    const int t = threadIdx.x;
    int vals[20];
    const int base = t * 20;
    int lsum = 0;
#pragma unroll
    for (int j = 0; j < 20; j++) {
        int idx = base + j;
        int v = (idx < NNODES) ? counts[idx] : 0;
        vals[j] = v; lsum += v;
    }
    sdata[t] = lsum;
    __syncthreads();
    for (int off = 1; off < 1024; off <<= 1) {
        int v = (t >= off) ? sdata[t - off] : 0;
        __syncthreads();
        sdata[t] += v;
        __syncthreads();
    }
    int run = sdata[t] - lsum;
#pragma unroll
    for (int j = 0; j < 20; j++) {
        int idx = base + j;
        if (idx < NNODES) row_ptr[idx] = run;
        run += vals[j];
    }
    if (t == 1023) row_ptr[NNODES] = sdata[1023];
}

__global__ void fill_kernel(const int* __restrict__ ei,
                            const int* __restrict__ row_ptr,
                            int* __restrict__ cursor,
                            int2* __restrict__ csr)   // {src, eid}
{
    int e = blockIdx.x * blockDim.x + threadIdx.x;
    if (e >= NEDGES) return;
    int dst = ei[NEDGES + e];
    int p = row_ptr[dst] + atomicAdd(&cursor[dst], 1);
    csr[p] = make_int2(ei[e], e);
}

__global__ void dinv_kernel(const int* __restrict__ row_ptr, float* __restrict__ dinv) {
    int i = blockIdx.x * blockDim.x + threadIdx.x;
    if (i < NNODES) {
        int deg = row_ptr[i + 1] - row_ptr[i] + 1;   // + self loop
        dinv[i] = rsqrtf((float)deg);
    }
}

// ---------------- packing ----------------
__global__ void pad_copy_kernel(const float* __restrict__ src,
                                unsigned short* __restrict__ dst,
                                int valid_rows, int cols, long total)
{
    long idx = (long)blockIdx.x * blockDim.x + threadIdx.x;
    if (idx >= total) return;
    int n = (int)(idx / cols);
    dst[idx] = (n < valid_rows) ? f2b(src[idx]) : (unsigned short)0;
}

__global__ void pack_cgw_kernel(const float* __restrict__ Wf,
                                const float* __restrict__ Ws,
                                unsigned short* __restrict__ out)
{
    int idx = blockIdx.x * blockDim.x + threadIdx.x;
    if (idx >= 2048 * 512) return;
    int j = idx >> 9;
    int k = idx & 511;
    float v;
    if (j < 512)       v = Wf[(size_t)k * 512 + j];
    else if (j < 1024) v = Wf[(size_t)(512 + k) * 512 + (j - 512)];
    else if (j < 1536) v = Ws[(size_t)k * 512 + (j - 1024)];
    else               v = Ws[(size_t)(512 + k) * 512 + (j - 1536)];
    out[idx] = f2b(v);
}

__global__ void pack_t_kernel(const float* __restrict__ W,
                              unsigned short* __restrict__ WT,
                              int K, int Nout)
{
    long idx = (long)blockIdx.x * blockDim.x + threadIdx.x;
    if (idx >= (long)K * Nout) return;
    int j = (int)(idx / K);
    int k = (int)(idx % K);
    WT[idx] = f2b(W[(size_t)k * Nout + j]);
}

// ---------------- CGConv gather (atomic-free, packed fp32 math) ----------------
// P (bf16) [n,0:512]=f_dst [512:1024]=f_src [1024:1536]=s_dst [1536:2048]=s_src
__global__ __launch_bounds__(256) void cg_gather_kernel(
    const unsigned short* __restrict__ P,
    const int* __restrict__ row_ptr,
    const int2* __restrict__ csr,
    const float* __restrict__ ea,
    const float* __restrict__ Wf,   // [1040,512], rows 1024.. = W_e
    const float* __restrict__ Ws,
    const float* __restrict__ bfv,
    const float* __restrict__ bsv,
    const float* __restrict__ g,
    const float* __restrict__ be,
    const float* __restrict__ xresf,          // fp32 [NNODES,512] or null
    const unsigned short* __restrict__ xresb, // bf16 [NPAD,512] or null
    unsigned short* __restrict__ hout)
{
    const int n   = blockIdx.x;
    const int tid = threadIdx.x;
    const int c0  = tid * 2;
    if (n >= NNODES) {
        *(unsigned int*)&hout[(size_t)n * 512 + c0] = 0;
        return;
    }
    f32x2 wf[16], wsv[16];
#pragma unroll
    for (int k = 0; k < 16; k++) {
        const size_t rb = (size_t)(1024 + k) * 512;
        wf[k]  = *(const f32x2*)&Wf[rb + c0];
        wsv[k] = *(const f32x2*)&Ws[rb + c0];
    }
    const unsigned short* Pd = P + (size_t)n * 2048;
    const f32x2 baseF = unpack2(*(const unsigned int*)(Pd + c0))        + *(const f32x2*)&bfv[c0];
    const f32x2 baseS = unpack2(*(const unsigned int*)(Pd + 1024 + c0)) + *(const f32x2*)&bsv[c0];

    f32x2 acc = {0.f, 0.f};
    const int i0 = row_ptr[n], i1 = row_ptr[n + 1];
    for (int i = i0; i < i1; i++) {
        const int2 se = csr[i];            // block-uniform -> scalar load
        const float* ep = ea + (size_t)se.y * 16;
        const unsigned short* Ps = P + (size_t)se.x * 2048;
        f32x2 f = baseF + unpack2(*(const unsigned int*)(Ps + 512 + c0));
        f32x2 s = baseS + unpack2(*(const unsigned int*)(Ps + 1536 + c0));
#pragma unroll
        for (int k = 0; k < 16; k++) {
            float ekk = ep[k];             // block-uniform scalar
            f32x2 ekv = {ekk, ekk};
            f = __builtin_elementwise_fma(ekv, wf[k], f);
            s = __builtin_elementwise_fma(ekv, wsv[k], s);
        }
        // m = softplus(s) * sigmoid(f); |s|,|f| bounded -> plain log(1+exp)
        float sp0 = __logf(1.f + __expf(s.x));
        float sp1 = __logf(1.f + __expf(s.y));
        float sg0 = __builtin_amdgcn_rcpf(1.f + __expf(-f.x));
        float sg1 = __builtin_amdgcn_rcpf(1.f + __expf(-f.y));
        acc.x = fmaf(sp0, sg0, acc.x);
        acc.y = fmaf(sp1, sg1, acc.y);
    }
    // fused BN(eval) + residual + ReLU
    const float rs = rsqrtf(1.f + 1e-5f);
    f32x2 res;
    if (xresf) {
        res = *(const f32x2*)&xresf[(size_t)n * 512 + c0];
    } else {
        res = unpack2(*(const unsigned int*)&xresb[(size_t)n * 512 + c0]);
    }
    const f32x2 gv  = *(const f32x2*)&g[c0];
    const f32x2 bev = *(const f32x2*)&be[c0];
    float v0 = fmaxf(acc.x * (gv.x * rs) + bev.x + res.x, 0.f);
    float v1 = fmaxf(acc.y * (gv.y * rs) + bev.y + res.y, 0.f);
    unsigned int packed = (unsigned int)f2b(v0) | ((unsigned int)f2b(v1) << 16);
    *(unsigned int*)&hout[(size_t)n * 512 + c0] = packed;
}

// ---------------- GCN gather (bf16 pre, fused combine) ----------------
__global__ __launch_bounds__(256) void gcn_gather_kernel(
    const unsigned short* __restrict__ pre,   // bf16 [NPAD,256]
    const int* __restrict__ row_ptr,
    const int2* __restrict__ csr,
    const float* __restrict__ dinv,
    const float* __restrict__ b,
    unsigned short* __restrict__ hout,  // bf16 [NPAD,256]
    float* __restrict__ doutf)          // fp32 [NNODES,256] or null
{
    const int n = blockIdx.x;
    const int c = threadIdx.x;
    if (n >= NNODES) {
        hout[(size_t)n * 256 + c] = 0;
        return;
    }
    const float din = dinv[n];
    float acc = 0.f;
    const int i0 = row_ptr[n], i1 = row_ptr[n + 1];
    for (int i = i0; i < i1; i++) {
        const int src = csr[i].x;
        acc = fmaf(dinv[src], b2f(pre[(size_t)src * 256 + c]), acc);
    }
    float self = b2f(pre[(size_t)n * 256 + c]);
    float v = fmaxf(acc * din + din * din * self + b[c], 0.f);
    hout[(size_t)n * 256 + c] = f2b(v);
    if (doutf) doutf[(size_t)n * 256 + c] = v;
}

// ---------------- MLP ----------------
__global__ void build_zc_kernel(const unsigned short* __restrict__ h4,
                                const float* __restrict__ goal,
                                unsigned short* __restrict__ zc)
{
    long idx = (long)blockIdx.x * blockDim.x + threadIdx.x;
    if (idx >= (long)NPAD * 768) return;
    int n = (int)(idx / 768);
    int c = (int)(idx % 768);
    unsigned short v = 0;
    if (n < NNODES)
        v = (c < 256) ? h4[(size_t)n * 256 + c]
                      : f2b(goal[(size_t)n * 512 + (c - 256)]);
    zc[idx] = v;
}

__global__ __launch_bounds__(256) void final_dot_kernel(
    const unsigned short* __restrict__ t,
    const float* __restrict__ Wd2,
    const float* __restrict__ bd2,
    float* __restrict__ pred)
{
    const int lane = threadIdx.x & 63;
    const int wid  = threadIdx.x >> 6;
    float w[8];
#pragma unroll
    for (int i = 0; i < 8; i++) w[i] = Wd2[lane * 8 + i];
    const float bd = bd2[0];
    for (int n = blockIdx.x * 4 + wid; n < NNODES; n += gridDim.x * 4) {
        const unsigned short* tp = t + (size_t)n * 512 + lane * 8;
        float s = 0.f;
#pragma unroll
        for (int i = 0; i < 8; i++) s = fmaf(b2f(tp[i]), w[i], s);
#pragma unroll
        for (int off = 32; off; off >>= 1) s += __shfl_xor(s, off, 64);
        if (lane == 0) pred[n] = s + bd;
    }
}

// ---------------- launcher ----------------
extern "C" void kernel_launch(void* const* d_in, const int* in_sizes, int n_in,
                              void* d_out, int out_size, void* d_ws, size_t ws_size,
                              hipStream_t stream)
{
    (void)in_sizes; (void)n_in; (void)out_size; (void)ws_size;
    const float* x    = (const float*)d_in[0];
    const int*   ei   = (const int*)d_in[1];
    const float* ea   = (const float*)d_in[2];
    const float* goal = (const float*)d_in[3];
    const float* Wf1  = (const float*)d_in[4];
    const float* bf1  = (const float*)d_in[5];
    const float* Ws1  = (const float*)d_in[6];
    const float* bs1  = (const float*)d_in[7];
    const float* g1   = (const float*)d_in[8];
    const float* be1  = (const float*)d_in[9];
    const float* Wf2  = (const float*)d_in[10];
    const float* bf2  = (const float*)d_in[11];
    const float* Ws2  = (const float*)d_in[12];
    const float* bs2  = (const float*)d_in[13];
    const float* g2   = (const float*)d_in[14];
    const float* be2  = (const float*)d_in[15];
    const float* W3   = (const float*)d_in[16];
    const float* b3   = (const float*)d_in[17];
    const float* W4   = (const float*)d_in[18];
    const float* b4   = (const float*)d_in[19];
    const float* Wd1  = (const float*)d_in[20];
    const float* bd1  = (const float*)d_in[21];
    const float* Wd2  = (const float*)d_in[22];
    const float* bd2  = (const float*)d_in[23];
    float* outp = (float*)d_out;   // fp32: [0..N) pred, [N..N+N*256) h

    char* ws = (char*)d_ws;
    size_t off = 0;
    auto alloc = [&](size_t bytes) -> char* {
        char* p = ws + off;
        off += (bytes + 255) & ~(size_t)255;
        return p;
    };
    unsigned short* P     = (unsigned short*)alloc((size_t)NPAD * 2048 * 2); // later zc + tb
    unsigned short* bufA  = (unsigned short*)alloc((size_t)NPAD * 512 * 2);  // xpad / h2 / h4
    unsigned short* bufB  = (unsigned short*)alloc((size_t)NPAD * 512 * 2);  // h1 / pre_b
    unsigned short* bufC  = (unsigned short*)alloc((size_t)NPAD * 512 * 2);  // h3
    unsigned short* wpack = (unsigned short*)alloc((size_t)2048 * 512 * 2);
    int*            counts  = (int*)alloc((size_t)NNODES * 4);
    int*            row_ptr = (int*)alloc((size_t)(NNODES + 1) * 4);
    int2*           csr     = (int2*)alloc((size_t)NEDGES * 8);
    float*          dinv    = (float*)alloc((size_t)NNODES * 4);

    unsigned short* xpad  = bufA;
    unsigned short* h1    = bufB;
    unsigned short* h2    = bufA;
    unsigned short* pre_b = bufB;
    unsigned short* h3    = bufC;
    unsigned short* h4    = bufA;
    unsigned short* zc    = P;
    unsigned short* tb    = P + (size_t)NPAD * 1024;

    const int B = 256;

    // ---- CSR build (by destination) + dinv ----
    hipMemsetAsync(counts, 0, (size_t)NNODES * 4, stream);
    count_kernel<<<(NEDGES + B - 1) / B, B, 0, stream>>>(ei, counts);
    scan_kernel<<<1, 1024, 0, stream>>>(counts, row_ptr);
    hipMemsetAsync(counts, 0, (size_t)NNODES * 4, stream);
    fill_kernel<<<(NEDGES + B - 1) / B, B, 0, stream>>>(ei, row_ptr, counts, csr);
    dinv_kernel<<<(NNODES + B - 1) / B, B, 0, stream>>>(row_ptr, dinv);

    {
        long tot = (long)NPAD * 512;
        pad_copy_kernel<<<(unsigned)((tot + B - 1) / B), B, 0, stream>>>(x, xpad, NNODES, 512, tot);
    }

    dim3 gBig(NPAD / 128, 2048 / 128);

    // ---- CGConv layer 1 ----
    pack_cgw_kernel<<<(2048 * 512 + B - 1) / B, B, 0, stream>>>(Wf1, Ws1, wpack);
    gemm_bt_kernel<<<gBig, B, 0, stream>>>(xpad, wpack, nullptr, P, NPAD, 2048, 512, nullptr);
    cg_gather_kernel<<<NPAD, B, 0, stream>>>(P, row_ptr, csr, ea,
                                             Wf1, Ws1, bf1, bs1, g1, be1,
                                             x, nullptr, h1);

    // ---- CGConv layer 2 ----
    pack_cgw_kernel<<<(2048 * 512 + B - 1) / B, B, 0, stream>>>(Wf2, Ws2, wpack);
    gemm_bt_kernel<<<gBig, B, 0, stream>>>(h1, wpack, nullptr, P, NPAD, 2048, 512, nullptr);
    cg_gather_kernel<<<NPAD, B, 0, stream>>>(P, row_ptr, csr, ea,
                                             Wf2, Ws2, bf2, bs2, g2, be2,
                                             nullptr, h1, h2);

    // ---- GCN layer 3 ----
    pack_t_kernel<<<(256 * 512 + B - 1) / B, B, 0, stream>>>(W3, wpack, 512, 256);
    gemm_bt_kernel<<<dim3(NPAD / 128, 2), B, 0, stream>>>(h2, wpack, nullptr, pre_b, NPAD, 256, 512, nullptr);
    gcn_gather_kernel<<<NPAD, B, 0, stream>>>(pre_b, row_ptr, csr, dinv, b3, h3, (float*)nullptr);

    // ---- GCN layer 4 ----
    pack_t_kernel<<<(256 * 256 + B - 1) / B, B, 0, stream>>>(W4, wpack, 256, 256);
    gemm_bt_kernel<<<dim3(NPAD / 128, 2), B, 0, stream>>>(h3, wpack, nullptr, pre_b, NPAD, 256, 256, nullptr);
    gcn_gather_kernel<<<NPAD, B, 0, stream>>>(pre_b, row_ptr, csr, dinv, b4, h4, outp + NNODES);

    // ---- distance MLP (bias+ReLU fused into GEMM epilogue) ----
    build_zc_kernel<<<(unsigned)(((long)NPAD * 768 + B - 1) / B), B, 0, stream>>>(h4, goal, zc);
    pack_t_kernel<<<(512 * 768 + B - 1) / B, B, 0, stream>>>(Wd1, wpack, 768, 512);
    gemm_bt_kernel<<<dim3(NPAD / 128, 4), B, 0, stream>>>(zc, wpack, nullptr, tb, NPAD, 512, 768, bd1);
    final_dot_kernel<<<512, B, 0, stream>>>(tb, Wd2, bd2, outp);
}

// Round 8
// 865.589 us; speedup vs baseline: 3.1409x; 1.0144x over previous
//
#include <hip/hip_runtime.h>
#include <stdint.h>

#define NNODES 20000
#define NEDGES 160000
#define NPAD   20096   // 157 * 128

typedef float f32x4 __attribute__((ext_vector_type(4)));
typedef float f32x2 __attribute__((ext_vector_type(2)));
typedef short s16x8 __attribute__((ext_vector_type(8)));

__device__ __forceinline__ float b2f(unsigned short b) {
    unsigned int u = ((unsigned int)b) << 16;
    return __builtin_bit_cast(float, u);
}
__device__ __forceinline__ unsigned short f2b(float f) {
    unsigned int u = __builtin_bit_cast(unsigned int, f);
    unsigned int r = (u + 0x7FFFu + ((u >> 16) & 1u)) >> 16;
    return (unsigned short)r;
}
// unpack 2 bf16 (packed in a dword) -> float2
__device__ __forceinline__ f32x2 unpack2(unsigned int u) {
    f32x2 r;
    r.x = __builtin_bit_cast(float, u << 16);
    r.y = __builtin_bit_cast(float, u & 0xFFFF0000u);
    return r;
}

// ---- GEMM: C[M,N] = A[M,K](bf16) @ BT[N,K]^T(bf16); C fp32 or bf16 ----
__global__ __launch_bounds__(256) void gemm_bt_kernel(
    const unsigned short* __restrict__ A,
    const unsigned short* __restrict__ BT,
    float* __restrict__ Cf,
    unsigned short* __restrict__ Cb,
    int M, int N, int K,
    const float* __restrict__ bias)
{
    __shared__ unsigned short As[128 * 32];
    __shared__ unsigned short Bs[128 * 32];
    const int tid  = threadIdx.x;
    const int wid  = tid >> 6;
    const int lane = tid & 63;
    const int bm = blockIdx.x * 128;
    const int bn = blockIdx.y * 128;
    const int wm = (wid & 1) * 64;
    const int wn = (wid >> 1) * 64;

    f32x4 acc[4][4];
#pragma unroll
    for (int i = 0; i < 4; i++)
#pragma unroll
        for (int j = 0; j < 4; j++) acc[i][j] = {0.f, 0.f, 0.f, 0.f};

    for (int k0 = 0; k0 < K; k0 += 32) {
#pragma unroll
        for (int r = 0; r < 2; r++) {
            int flat = r * 256 + tid;
            int row  = flat >> 2;
            int part = flat & 3;
            const unsigned short* ga = A  + (size_t)(bm + row) * K + k0 + part * 8;
            const unsigned short* gb = BT + (size_t)(bn + row) * K + k0 + part * 8;
            __builtin_amdgcn_global_load_lds(
                (const __attribute__((address_space(1))) unsigned int*)ga,
                (__attribute__((address_space(3))) unsigned int*)&As[flat * 8], 16, 0, 0);
            __builtin_amdgcn_global_load_lds(
                (const __attribute__((address_space(1))) unsigned int*)gb,
                (__attribute__((address_space(3))) unsigned int*)&Bs[flat * 8], 16, 0, 0);
        }
        __syncthreads();

        const int kq = (lane >> 4) * 8;
        const int rl = lane & 15;
        s16x8 af[4], bfr[4];
#pragma unroll
        for (int mi = 0; mi < 4; mi++)
            af[mi] = *(const s16x8*)&As[(wm + mi * 16 + rl) * 32 + kq];
#pragma unroll
        for (int ni = 0; ni < 4; ni++)
            bfr[ni] = *(const s16x8*)&Bs[(wn + ni * 16 + rl) * 32 + kq];
#pragma unroll
        for (int mi = 0; mi < 4; mi++)
#pragma unroll
            for (int ni = 0; ni < 4; ni++)
                acc[mi][ni] = __builtin_amdgcn_mfma_f32_16x16x32_bf16(
                    af[mi], bfr[ni], acc[mi][ni], 0, 0, 0);
        __syncthreads();
    }

    const int cl = lane & 15;
    const int rq = (lane >> 4) * 4;
#pragma unroll
    for (int mi = 0; mi < 4; mi++)
#pragma unroll
        for (int ni = 0; ni < 4; ni++)
#pragma unroll
            for (int r = 0; r < 4; r++) {
                int row = bm + wm + mi * 16 + rq + r;
                int col = bn + wn + ni * 16 + cl;
                float v = acc[mi][ni][r];
                if (Cb) {
                    if (bias) v = fmaxf(v + bias[col], 0.f);
                    Cb[(size_t)row * N + col] = f2b(v);
                } else {
                    Cf[(size_t)row * N + col] = v;
                }
            }
}

// ---------------- CSR build ----------------
__global__ void count_kernel(const int* __restrict__ ei, int* __restrict__ counts) {
    int e = blockIdx.x * blockDim.x + threadIdx.x;
    if (e < NEDGES) atomicAdd(&counts[ei[NEDGES + e]], 1);
}

__global__ __launch_bounds__(1024) void scan_kernel(const int* __restrict__ counts,
                                                    int* __restrict__ row_ptr)
{
    __shared__ int sdata[1024];
    const int t = threadIdx.x;
    int vals[20];
    const int base = t * 20;
    int lsum = 0;
#pragma unroll
    for (int j = 0; j < 20; j++) {
        int idx = base + j;
        int v = (idx < NNODES) ? counts[idx] : 0;
        vals[j] = v; lsum += v;
    }
    sdata[t] = lsum;
    __syncthreads();
    for (int off = 1; off < 1024; off <<= 1) {
        int v = (t >= off) ? sdata[t - off] : 0;
        __syncthreads();
        sdata[t] += v;
        __syncthreads();
    }
    int run = sdata[t] - lsum;
#pragma unroll
    for (int j = 0; j < 20; j++) {
        int idx = base + j;
        if (idx < NNODES) row_ptr[idx] = run;
        run += vals[j];
    }
    if (t == 1023) row_ptr[NNODES] = sdata[1023];
}

__global__ void fill_kernel(const int* __restrict__ ei,
                            const int* __restrict__ row_ptr,
                            int* __restrict__ cursor,
                            int2* __restrict__ csr)   // {src, eid}
{
    int e = blockIdx.x * blockDim.x + threadIdx.x;
    if (e >= NEDGES) return;
    int dst = ei[NEDGES + e];
    int p = row_ptr[dst] + atomicAdd(&cursor[dst], 1);
    csr[p] = make_int2(ei[e], e);
}

__global__ void dinv_kernel(const int* __restrict__ row_ptr, float* __restrict__ dinv) {
    int i = blockIdx.x * blockDim.x + threadIdx.x;
    if (i < NNODES) {
        int deg = row_ptr[i + 1] - row_ptr[i] + 1;   // + self loop
        dinv[i] = rsqrtf((float)deg);
    }
}

// ---------------- packing ----------------
__global__ void pad_copy_kernel(const float* __restrict__ src,
                                unsigned short* __restrict__ dst,
                                int valid_rows, int cols, long total)
{
    long idx = (long)blockIdx.x * blockDim.x + threadIdx.x;
    if (idx >= total) return;
    int n = (int)(idx / cols);
    dst[idx] = (n < valid_rows) ? f2b(src[idx]) : (unsigned short)0;
}

__global__ void pack_cgw_kernel(const float* __restrict__ Wf,
                                const float* __restrict__ Ws,
                                unsigned short* __restrict__ out)
{
    int idx = blockIdx.x * blockDim.x + threadIdx.x;
    if (idx >= 2048 * 512) return;
    int j = idx >> 9;
    int k = idx & 511;
    float v;
    if (j < 512)       v = Wf[(size_t)k * 512 + j];
    else if (j < 1024) v = Wf[(size_t)(512 + k) * 512 + (j - 512)];
    else if (j < 1536) v = Ws[(size_t)k * 512 + (j - 1024)];
    else               v = Ws[(size_t)(512 + k) * 512 + (j - 1536)];
    out[idx] = f2b(v);
}

__global__ void pack_t_kernel(const float* __restrict__ W,
                              unsigned short* __restrict__ WT,
                              int K, int Nout)
{
    long idx = (long)blockIdx.x * blockDim.x + threadIdx.x;
    if (idx >= (long)K * Nout) return;
    int j = (int)(idx / K);
    int k = (int)(idx % K);
    WT[idx] = f2b(W[(size_t)k * Nout + j]);
}

// ---------------- CGConv gather (registers-resident weights + prefetch) ----------------
// P (bf16) [n,0:512]=f_dst [512:1024]=f_src [1024:1536]=s_dst [1536:2048]=s_src
__global__ __launch_bounds__(256, 1) void cg_gather_kernel(
    const unsigned short* __restrict__ P,
    const int* __restrict__ row_ptr,
    const int2* __restrict__ csr,
    const float* __restrict__ ea,
    const float* __restrict__ Wf,   // [1040,512], rows 1024.. = W_e
    const float* __restrict__ Ws,
    const float* __restrict__ bfv,
    const float* __restrict__ bsv,
    const float* __restrict__ g,
    const float* __restrict__ be,
    const float* __restrict__ xresf,          // fp32 [NNODES,512] or null
    const unsigned short* __restrict__ xresb, // bf16 [NPAD,512] or null
    unsigned short* __restrict__ hout)
{
    const int n   = blockIdx.x;
    const int tid = threadIdx.x;
    const int c0  = tid * 2;
    if (n >= NNODES) {
        *(unsigned int*)&hout[(size_t)n * 512 + c0] = 0;
        return;
    }
    // weights resident in VGPRs (64 regs) — launch_bounds(256,1) lifts the cap
    f32x2 wf[16], wsv[16];
#pragma unroll
    for (int k = 0; k < 16; k++) {
        const size_t rb = (size_t)(1024 + k) * 512;
        wf[k]  = *(const f32x2*)&Wf[rb + c0];
        wsv[k] = *(const f32x2*)&Ws[rb + c0];
    }
    const unsigned short* Pd = P + (size_t)n * 2048;
    const f32x2 baseF = unpack2(*(const unsigned int*)(Pd + c0))        + *(const f32x2*)&bfv[c0];
    const f32x2 baseS = unpack2(*(const unsigned int*)(Pd + 1024 + c0)) + *(const f32x2*)&bsv[c0];

    f32x2 acc = {0.f, 0.f};
    const int i0 = row_ptr[n], i1 = row_ptr[n + 1];

    if (i0 < i1) {
        // prologue: load edge i0
        int2 se = csr[i0];
        {
            const float4* ep = (const float4*)(ea + (size_t)se.y * 16);
            const unsigned short* Ps = P + (size_t)se.x * 2048;
            float4 e0 = ep[0], e1 = ep[1], e2 = ep[2], e3 = ep[3];
            unsigned int pf = *(const unsigned int*)(Ps + 512 + c0);
            unsigned int ps = *(const unsigned int*)(Ps + 1536 + c0);

            for (int i = i0; i < i1; i++) {
                // copy current, prefetch next (overlaps with compute below)
                float4 c0v = e0, c1v = e1, c2v = e2, c3v = e3;
                unsigned int cpf = pf, cps = ps;
                if (i + 1 < i1) {
                    int2 se2 = csr[i + 1];
                    const float4* ep2 = (const float4*)(ea + (size_t)se2.y * 16);
                    const unsigned short* Ps2 = P + (size_t)se2.x * 2048;
                    e0 = ep2[0]; e1 = ep2[1]; e2 = ep2[2]; e3 = ep2[3];
                    pf = *(const unsigned int*)(Ps2 + 512 + c0);
                    ps = *(const unsigned int*)(Ps2 + 1536 + c0);
                }
                f32x2 f = baseF + unpack2(cpf);
                f32x2 s = baseS + unpack2(cps);
                const float ek[16] = {c0v.x, c0v.y, c0v.z, c0v.w,
                                      c1v.x, c1v.y, c1v.z, c1v.w,
                                      c2v.x, c2v.y, c2v.z, c2v.w,
                                      c3v.x, c3v.y, c3v.z, c3v.w};
#pragma unroll
                for (int k = 0; k < 16; k++) {
                    f32x2 ev = {ek[k], ek[k]};
                    f = __builtin_elementwise_fma(ev, wf[k], f);
                    s = __builtin_elementwise_fma(ev, wsv[k], s);
                }
                float sp0 = __logf(1.f + __expf(s.x));
                float sp1 = __logf(1.f + __expf(s.y));
                float sg0 = __builtin_amdgcn_rcpf(1.f + __expf(-f.x));
                float sg1 = __builtin_amdgcn_rcpf(1.f + __expf(-f.y));
                acc.x = fmaf(sp0, sg0, acc.x);
                acc.y = fmaf(sp1, sg1, acc.y);
            }
        }
    }
    // fused BN(eval) + residual + ReLU
    const float rs = rsqrtf(1.f + 1e-5f);
    f32x2 res;
    if (xresf) {
        res = *(const f32x2*)&xresf[(size_t)n * 512 + c0];
    } else {
        res = unpack2(*(const unsigned int*)&xresb[(size_t)n * 512 + c0]);
    }
    const f32x2 gv  = *(const f32x2*)&g[c0];
    const f32x2 bev = *(const f32x2*)&be[c0];
    float v0 = fmaxf(acc.x * (gv.x * rs) + bev.x + res.x, 0.f);
    float v1 = fmaxf(acc.y * (gv.y * rs) + bev.y + res.y, 0.f);
    unsigned int packed = (unsigned int)f2b(v0) | ((unsigned int)f2b(v1) << 16);
    *(unsigned int*)&hout[(size_t)n * 512 + c0] = packed;
}

// ---------------- GCN gather (bf16 pre, fused combine) ----------------
__global__ __launch_bounds__(256) void gcn_gather_kernel(
    const unsigned short* __restrict__ pre,   // bf16 [NPAD,256]
    const int* __restrict__ row_ptr,
    const int2* __restrict__ csr,
    const float* __restrict__ dinv,
    const float* __restrict__ b,
    unsigned short* __restrict__ hout,  // bf16 [NPAD,256]
    float* __restrict__ doutf)          // fp32 [NNODES,256] or null
{
    const int n = blockIdx.x;
    const int c = threadIdx.x;
    if (n >= NNODES) {
        hout[(size_t)n * 256 + c] = 0;
        return;
    }
    const float din = dinv[n];
    float acc = 0.f;
    const int i0 = row_ptr[n], i1 = row_ptr[n + 1];
    for (int i = i0; i < i1; i++) {
        const int src = csr[i].x;
        acc = fmaf(dinv[src], b2f(pre[(size_t)src * 256 + c]), acc);
    }
    float self = b2f(pre[(size_t)n * 256 + c]);
    float v = fmaxf(acc * din + din * din * self + b[c], 0.f);
    hout[(size_t)n * 256 + c] = f2b(v);
    if (doutf) doutf[(size_t)n * 256 + c] = v;
}

// ---------------- MLP ----------------
__global__ void build_zc_kernel(const unsigned short* __restrict__ h4,
                                const float* __restrict__ goal,
                                unsigned short* __restrict__ zc)
{
    long idx = (long)blockIdx.x * blockDim.x + threadIdx.x;
    if (idx >= (long)NPAD * 768) return;
    int n = (int)(idx / 768);
    int c = (int)(idx % 768);
    unsigned short v = 0;
    if (n < NNODES)
        v = (c < 256) ? h4[(size_t)n * 256 + c]
                      : f2b(goal[(size_t)n * 512 + (c - 256)]);
    zc[idx] = v;
}

__global__ __launch_bounds__(256) void final_dot_kernel(
    const unsigned short* __restrict__ t,
    const float* __restrict__ Wd2,
    const float* __restrict__ bd2,
    float* __restrict__ pred)
{
    const int lane = threadIdx.x & 63;
    const int wid  = threadIdx.x >> 6;
    float w[8];
#pragma unroll
    for (int i = 0; i < 8; i++) w[i] = Wd2[lane * 8 + i];
    const float bd = bd2[0];
    for (int n = blockIdx.x * 4 + wid; n < NNODES; n += gridDim.x * 4) {
        const unsigned short* tp = t + (size_t)n * 512 + lane * 8;
        float s = 0.f;
#pragma unroll
        for (int i = 0; i < 8; i++) s = fmaf(b2f(tp[i]), w[i], s);
#pragma unroll
        for (int off = 32; off; off >>= 1) s += __shfl_xor(s, off, 64);
        if (lane == 0) pred[n] = s + bd;
    }
}

// ---------------- launcher ----------------
extern "C" void kernel_launch(void* const* d_in, const int* in_sizes, int n_in,
                              void* d_out, int out_size, void* d_ws, size_t ws_size,
                              hipStream_t stream)
{
    (void)in_sizes; (void)n_in; (void)out_size; (void)ws_size;
    const float* x    = (const float*)d_in[0];
    const int*   ei   = (const int*)d_in[1];
    const float* ea   = (const float*)d_in[2];
    const float* goal = (const float*)d_in[3];
    const float* Wf1  = (const float*)d_in[4];
    const float* bf1  = (const float*)d_in[5];
    const float* Ws1  = (const float*)d_in[6];
    const float* bs1  = (const float*)d_in[7];
    const float* g1   = (const float*)d_in[8];
    const float* be1  = (const float*)d_in[9];
    const float* Wf2  = (const float*)d_in[10];
    const float* bf2  = (const float*)d_in[11];
    const float* Ws2  = (const float*)d_in[12];
    const float* bs2  = (const float*)d_in[13];
    const float* g2   = (const float*)d_in[14];
    const float* be2  = (const float*)d_in[15];
    const float* W3   = (const float*)d_in[16];
    const float* b3   = (const float*)d_in[17];
    const float* W4   = (const float*)d_in[18];
    const float* b4   = (const float*)d_in[19];
    const float* Wd1  = (const float*)d_in[20];
    const float* bd1  = (const float*)d_in[21];
    const float* Wd2  = (const float*)d_in[22];
    const float* bd2  = (const float*)d_in[23];
    float* outp = (float*)d_out;   // fp32: [0..N) pred, [N..N+N*256) h

    char* ws = (char*)d_ws;
    size_t off = 0;
    auto alloc = [&](size_t bytes) -> char* {
        char* p = ws + off;
        off += (bytes + 255) & ~(size_t)255;
        return p;
    };
    unsigned short* P     = (unsigned short*)alloc((size_t)NPAD * 2048 * 2); // later zc + tb
    unsigned short* bufA  = (unsigned short*)alloc((size_t)NPAD * 512 * 2);  // xpad / h2 / h4
    unsigned short* bufB  = (unsigned short*)alloc((size_t)NPAD * 512 * 2);  // h1 / pre_b
    unsigned short* bufC  = (unsigned short*)alloc((size_t)NPAD * 512 * 2);  // h3
    unsigned short* wpack = (unsigned short*)alloc((size_t)2048 * 512 * 2);
    int*            counts  = (int*)alloc((size_t)NNODES * 4);
    int*            row_ptr = (int*)alloc((size_t)(NNODES + 1) * 4);
    int2*           csr     = (int2*)alloc((size_t)NEDGES * 8);
    float*          dinv    = (float*)alloc((size_t)NNODES * 4);

    unsigned short* xpad  = bufA;
    unsigned short* h1    = bufB;
    unsigned short* h2    = bufA;
    unsigned short* pre_b = bufB;
    unsigned short* h3    = bufC;
    unsigned short* h4    = bufA;
    unsigned short* zc    = P;
    unsigned short* tb    = P + (size_t)NPAD * 1024;

    const int B = 256;

    // ---- CSR build (by destination) + dinv ----
    hipMemsetAsync(counts, 0, (size_t)NNODES * 4, stream);
    count_kernel<<<(NEDGES + B - 1) / B, B, 0, stream>>>(ei, counts);
    scan_kernel<<<1, 1024, 0, stream>>>(counts, row_ptr);
    hipMemsetAsync(counts, 0, (size_t)NNODES * 4, stream);
    fill_kernel<<<(NEDGES + B - 1) / B, B, 0, stream>>>(ei, row_ptr, counts, csr);
    dinv_kernel<<<(NNODES + B - 1) / B, B, 0, stream>>>(row_ptr, dinv);

    {
        long tot = (long)NPAD * 512;
        pad_copy_kernel<<<(unsigned)((tot + B - 1) / B), B, 0, stream>>>(x, xpad, NNODES, 512, tot);
    }

    dim3 gBig(NPAD / 128, 2048 / 128);

    // ---- CGConv layer 1 ----
    pack_cgw_kernel<<<(2048 * 512 + B - 1) / B, B, 0, stream>>>(Wf1, Ws1, wpack);
    gemm_bt_kernel<<<gBig, B, 0, stream>>>(xpad, wpack, nullptr, P, NPAD, 2048, 512, nullptr);
    cg_gather_kernel<<<NPAD, B, 0, stream>>>(P, row_ptr, csr, ea,
                                             Wf1, Ws1, bf1, bs1, g1, be1,
                                             x, nullptr, h1);

    // ---- CGConv layer 2 ----
    pack_cgw_kernel<<<(2048 * 512 + B - 1) / B, B, 0, stream>>>(Wf2, Ws2, wpack);
    gemm_bt_kernel<<<gBig, B, 0, stream>>>(h1, wpack, nullptr, P, NPAD, 2048, 512, nullptr);
    cg_gather_kernel<<<NPAD, B, 0, stream>>>(P, row_ptr, csr, ea,
                                             Wf2, Ws2, bf2, bs2, g2, be2,
                                             nullptr, h1, h2);

    // ---- GCN layer 3 ----
    pack_t_kernel<<<(256 * 512 + B - 1) / B, B, 0, stream>>>(W3, wpack, 512, 256);
    gemm_bt_kernel<<<dim3(NPAD / 128, 2), B, 0, stream>>>(h2, wpack, nullptr, pre_b, NPAD, 256, 512, nullptr);
    gcn_gather_kernel<<<NPAD, B, 0, stream>>>(pre_b, row_ptr, csr, dinv, b3, h3, (float*)nullptr);

    // ---- GCN layer 4 ----
    pack_t_kernel<<<(256 * 256 + B - 1) / B, B, 0, stream>>>(W4, wpack, 256, 256);
    gemm_bt_kernel<<<dim3(NPAD / 128, 2), B, 0, stream>>>(h3, wpack, nullptr, pre_b, NPAD, 256, 256, nullptr);
    gcn_gather_kernel<<<NPAD, B, 0, stream>>>(pre_b, row_ptr, csr, dinv, b4, h4, outp + NNODES);

    // ---- distance MLP (bias+ReLU fused into GEMM epilogue) ----
    build_zc_kernel<<<(unsigned)(((long)NPAD * 768 + B - 1) / B), B, 0, stream>>>(h4, goal, zc);
    pack_t_kernel<<<(512 * 768 + B - 1) / B, B, 0, stream>>>(Wd1, wpack, 768, 512);
    gemm_bt_kernel<<<dim3(NPAD / 128, 4), B, 0, stream>>>(zc, wpack, nullptr, tb, NPAD, 512, 768, bd1);
    final_dot_kernel<<<512, B, 0, stream>>>(tb, Wd2, bd2, outp);
}